// Round 2
// 1112.363 us; speedup vs baseline: 1.0920x; 1.0920x over previous
//
#include <hip/hip_runtime.h>

// Elman RNN, B=256,T=256,I=128,H=512,O=1.
// v3 = v2 (hoisted x-projection GEMM + ping-pong h + 1 barrier/step) with a
// ws_size guard: the 128.5 MB fast path only runs if the workspace is big
// enough; otherwise fall back to the round-0 kernel (640 KB ws, known-good).
// Suspected round-1 failure: xp (128 MB) written past end of d_ws.

#define B_   256
#define T_   256
#define I_   128
#define H_   512

typedef __attribute__((ext_vector_type(8))) short short8;
typedef __attribute__((ext_vector_type(4))) float f32x4;

static __device__ inline unsigned short f2bf(float f) {
    union { float f; unsigned u; } v; v.f = f;
    unsigned r = v.u + 0x7fffu + ((v.u >> 16) & 1u);   // RNE
    return (unsigned short)(r >> 16);
}
static __device__ inline float bf2f(unsigned short s) {
    union { unsigned u; float f; } v; v.u = ((unsigned)s) << 16;
    return v.f;
}
static __device__ inline float fast_tanh(float x) {
    float e = __expf(2.0f * x);
    return 1.0f - 2.0f / (e + 1.0f);
}

// ---------------------------------------------------------------------------
// FAST PATH (needs 512 KB + 128 MB workspace)
// ---------------------------------------------------------------------------
#define NKC   16   // K chunks of 32 covering W_hh (512)
#define RS2  520   // LDS h-row stride in bf16 elems (512 + 8 pad)
#define KC_LDS 3   // kc 0..2  in LDS (96 KB)
#define KC_REG 8   // kc 3..10 intended VGPR-resident
#define KC_STR 5   // kc 11..15 streamed from L2, 4-deep prefetch

// Bpack[( (nt*NKC + kc)*64 + lane )*8 + e] = W_hh[n*H + k] as bf16
//   k = kc*32 + (lane>>4)*8 + e,  n = nt*16 + (lane&15)
__global__ void pack_w16(const float* __restrict__ W_hh,
                         unsigned short* __restrict__ Bpack) {
    int idx = blockIdx.x * blockDim.x + threadIdx.x;
    if (idx >= 32 * NKC * 64) return;
    int lane = idx & 63;
    int kc   = (idx >> 6) % NKC;
    int nt   = (idx >> 6) / NKC;
    int n  = nt * 16 + (lane & 15);
    int k0 = kc * 32 + (lane >> 4) * 8;
    unsigned short* dst = Bpack + (size_t)idx * 8;
#pragma unroll
    for (int e = 0; e < 8; ++e)
        dst[e] = f2bf(W_hh[n * H_ + k0 + e]);
}

// xp[t][n][b] = sum_i x[b][t][i] * W_ih[n][i] + b_ih[n] + b_hh[n]   (f32)
__global__ __launch_bounds__(256)
void xproj_k(const float* __restrict__ x,
             const float* __restrict__ W_ih,
             const float* __restrict__ b_ih,
             const float* __restrict__ b_hh,
             float* __restrict__ xp) {
    const int tid  = threadIdx.x;
    const int lane = tid & 63;
    const int w    = tid >> 6;
    const int mr   = lane & 15;
    const int q    = lane >> 4;
    const int t    = blockIdx.x;
    const int ng   = blockIdx.y;            // 0..3
    const int bt   = blockIdx.z * 4 + w;    // 0..15

    // B fragments from x: col b = 16*bt+mr, k = i = kc*32 + q*8 + e
    short8 bf[4];
    const float* xb = x + ((size_t)(16 * bt + mr) * T_ + t) * I_ + q * 8;
#pragma unroll
    for (int kc = 0; kc < 4; ++kc) {
        float4 lo = *(const float4*)(xb + kc * 32);
        float4 hi = *(const float4*)(xb + kc * 32 + 4);
        short8 v;
        v[0] = (short)f2bf(lo.x); v[1] = (short)f2bf(lo.y);
        v[2] = (short)f2bf(lo.z); v[3] = (short)f2bf(lo.w);
        v[4] = (short)f2bf(hi.x); v[5] = (short)f2bf(hi.y);
        v[6] = (short)f2bf(hi.z); v[7] = (short)f2bf(hi.w);
        bf[kc] = v;
    }

    f32x4 acc[8];
#pragma unroll
    for (int j = 0; j < 8; ++j) acc[j] = (f32x4)(0.0f);

#pragma unroll
    for (int kc = 0; kc < 4; ++kc) {
#pragma unroll
        for (int j = 0; j < 8; ++j) {
            const float* ab = W_ih + (size_t)(ng * 128 + j * 16 + mr) * I_ + kc * 32 + q * 8;
            float4 lo = *(const float4*)(ab);
            float4 hi = *(const float4*)(ab + 4);
            short8 af;
            af[0] = (short)f2bf(lo.x); af[1] = (short)f2bf(lo.y);
            af[2] = (short)f2bf(lo.z); af[3] = (short)f2bf(lo.w);
            af[4] = (short)f2bf(hi.x); af[5] = (short)f2bf(hi.y);
            af[6] = (short)f2bf(hi.z); af[7] = (short)f2bf(hi.w);
            acc[j] = __builtin_amdgcn_mfma_f32_16x16x32_bf16(af, bf[kc], acc[j], 0, 0, 0);
        }
    }

    // D: col = b = 16*bt + mr, row = n_local = q*4 + e
#pragma unroll
    for (int j = 0; j < 8; ++j) {
#pragma unroll
        for (int e = 0; e < 4; ++e) {
            int n = ng * 128 + j * 16 + q * 4 + e;
            float bv = b_ih[n] + b_hh[n];
            xp[((size_t)t * H_ + n) * B_ + 16 * bt + mr] = acc[j][e] + bv;
        }
    }
}

__global__ __launch_bounds__(512, 2)
void rnn_fast(const unsigned short* __restrict__ Bpack,
              const float* __restrict__ xp,
              const float* __restrict__ fc_w,
              const float* __restrict__ fc_b,
              float* __restrict__ out) {
    __shared__ __align__(16) unsigned short a_lds[2][16 * RS2];            // 33.3 KB
    __shared__ __align__(16) unsigned short w_lds[32 * KC_LDS * 64 * 8];   // 96 KB

    const int tid  = threadIdx.x;
    const int lane = tid & 63;
    const int w    = tid >> 6;      // wave 0..7, owns cols [64w, 64w+64)
    const int q    = lane >> 4;     // 0..3
    const int mr   = lane & 15;
    const int bb   = blockIdx.x * 16;

    // h0 = 0
    for (int i = tid; i < 16 * RS2; i += 512) a_lds[0][i] = 0;

    // preload LDS-resident W chunks (kc 0..2), fragment layout
    for (int i = tid; i < 32 * KC_LDS * 64; i += 512) {
        int l  = i & 63;
        int kc = (i >> 6) % KC_LDS;
        int nt = (i >> 6) / KC_LDS;
        *(short8*)&w_lds[(size_t)i * 8] =
            *(const short8*)(Bpack + ((size_t)(nt * NKC + kc) * 64 + l) * 8);
    }

    // register-resident W_hh kc 3..10
    short8 wreg[KC_REG][4];
#pragma unroll
    for (int r = 0; r < KC_REG; ++r)
#pragma unroll
        for (int j = 0; j < 4; ++j)
            wreg[r][j] = *(const short8*)(Bpack +
                ((size_t)((4 * w + j) * NKC + KC_LDS + r) * 64 + lane) * 8);

    __syncthreads();  // a_lds[0] zeros + w_lds visible

    f32x4 acc[4];
    short8 sb[4][4];   // streamed prefetch buffers (4 kc in flight)

    for (int t = 0; t < T_; ++t) {
        const unsigned short* A = a_lds[t & 1];
        unsigned short* An      = a_lds[(t & 1) ^ 1];

        // streamed W issue: kc 11..14 (4-deep)
#pragma unroll
        for (int s = 0; s < 4; ++s)
#pragma unroll
            for (int j = 0; j < 4; ++j)
                sb[s][j] = *(const short8*)(Bpack +
                    ((size_t)((4 * w + j) * NKC + KC_LDS + KC_REG + s) * 64 + lane) * 8);

        // xp prefetch (consumed in epilogue)
        f32x4 xpr[4];
#pragma unroll
        for (int j = 0; j < 4; ++j) {
            int col = (4 * w + j) * 16 + mr;
            xpr[j] = *(const f32x4*)(xp + ((size_t)t * H_ + col) * B_ + bb + 4 * q);
        }

#pragma unroll
        for (int j = 0; j < 4; ++j) acc[j] = (f32x4)(0.0f);

        // --- LDS-resident kcs (0..2) ---
#pragma unroll
        for (int kc = 0; kc < KC_LDS; ++kc) {
            short8 af = *(const short8*)&A[mr * RS2 + kc * 32 + q * 8];
#pragma unroll
            for (int j = 0; j < 4; ++j) {
                short8 bfr = *(const short8*)&w_lds[
                    (size_t)(((4 * w + j) * KC_LDS + kc) * 64 + lane) * 8];
                acc[j] = __builtin_amdgcn_mfma_f32_16x16x32_bf16(af, bfr, acc[j], 0, 0, 0);
            }
        }
        // --- register-resident kcs (3..10) ---
#pragma unroll
        for (int r = 0; r < KC_REG; ++r) {
            short8 af = *(const short8*)&A[mr * RS2 + (KC_LDS + r) * 32 + q * 8];
#pragma unroll
            for (int j = 0; j < 4; ++j)
                acc[j] = __builtin_amdgcn_mfma_f32_16x16x32_bf16(af, wreg[r][j], acc[j], 0, 0, 0);
        }
        // --- streamed kcs (11..15), refill sb[0] for kc 15 ---
#pragma unroll
        for (int s = 0; s < KC_STR; ++s) {
            int kc = KC_LDS + KC_REG + s;
            short8 af = *(const short8*)&A[mr * RS2 + kc * 32 + q * 8];
#pragma unroll
            for (int j = 0; j < 4; ++j)
                acc[j] = __builtin_amdgcn_mfma_f32_16x16x32_bf16(af, sb[s & 3][j], acc[j], 0, 0, 0);
            if (s + 4 < KC_STR) {
#pragma unroll
                for (int j = 0; j < 4; ++j)
                    sb[s & 3][j] = *(const short8*)(Bpack +
                        ((size_t)((4 * w + j) * NKC + kc + 4) * 64 + lane) * 8);
            }
        }

        // epilogue: h_{t+1} = tanh(acc + xp); D row m = q*4+e, col = (4w+j)*16+mr
#pragma unroll
        for (int j = 0; j < 4; ++j) {
            int col = (4 * w + j) * 16 + mr;
#pragma unroll
            for (int e = 0; e < 4; ++e) {
                float hv = fast_tanh(acc[j][e] + xpr[j][e]);
                An[(q * 4 + e) * RS2 + col] = f2bf(hv);
            }
        }
        __syncthreads();   // h_{t+1} visible; fences A reads vs next overwrite
    }
    __syncthreads();

    // out[b] = h_T[b] . fc_w + fc_b  (32 threads per batch row); h_T in buf 0 (T even)
    {
        const int row = tid >> 5;
        const int l32 = tid & 31;
        float s = 0.0f;
        for (int k = l32; k < H_; k += 32)
            s += bf2f(a_lds[0][row * RS2 + k]) * fc_w[k];
#pragma unroll
        for (int off = 16; off > 0; off >>= 1)
            s += __shfl_down(s, off, 32);
        if (l32 == 0) out[bb + row] = s + fc_b[0];
    }
}

// ---------------------------------------------------------------------------
// FALLBACK PATH — round-0 kernel verbatim (640 KB workspace, measured 1214 µs)
// ---------------------------------------------------------------------------
#define FB_NKC   20
#define FB_NKC_H 16
#define FB_RS   648
#define FB_KC_LDS 4
#define FB_KC_REG 5
#define FB_KC_STR 7

__global__ void pack_w20(const float* __restrict__ W_ih,
                         const float* __restrict__ W_hh,
                         unsigned short* __restrict__ Bpack) {
    int idx = blockIdx.x * blockDim.x + threadIdx.x;
    if (idx >= 32 * FB_NKC * 64) return;
    int lane = idx & 63;
    int kc   = (idx >> 6) % FB_NKC;
    int nt   = (idx >> 6) / FB_NKC;
    int n  = nt * 16 + (lane & 15);
    int k0 = kc * 32 + (lane >> 4) * 8;
    unsigned short* dst = Bpack + (size_t)idx * 8;
#pragma unroll
    for (int e = 0; e < 8; ++e) {
        int k = k0 + e;
        float v = (k < H_) ? W_hh[n * H_ + k] : W_ih[n * I_ + (k - H_)];
        dst[e] = f2bf(v);
    }
}

__global__ __launch_bounds__(512, 2)
void rnn_fb(const float* __restrict__ x,
            const unsigned short* __restrict__ Bpack,
            const float* __restrict__ b_ih,
            const float* __restrict__ b_hh,
            const float* __restrict__ fc_w,
            const float* __restrict__ fc_b,
            float* __restrict__ out) {
    __shared__ __align__(16) unsigned short a_lds[16 * FB_RS];
    __shared__ __align__(16) unsigned short w_lds[32 * FB_KC_LDS * 64 * 8];

    const int tid  = threadIdx.x;
    const int lane = tid & 63;
    const int w    = tid >> 6;
    const int q    = lane >> 4;
    const int mr   = lane & 15;
    const int bb   = blockIdx.x * 16;

    for (int i = tid; i < 16 * FB_RS; i += 512) a_lds[i] = 0;

    for (int i = tid; i < 32 * FB_KC_LDS * 64; i += 512) {
        int l  = i & 63;
        int kc = (i >> 6) & (FB_KC_LDS - 1);
        int nt = i >> 8;
        *(short8*)&w_lds[(size_t)i * 8] =
            *(const short8*)(Bpack + ((size_t)(nt * FB_NKC + kc) * 64 + l) * 8);
    }

    float bias[4];
#pragma unroll
    for (int j = 0; j < 4; ++j) {
        int col = (4 * w + j) * 16 + mr;
        bias[j] = b_ih[col] + b_hh[col];
    }

    short8 wih[4][4];
#pragma unroll
    for (int j = 0; j < 4; ++j)
#pragma unroll
        for (int kx = 0; kx < 4; ++kx)
            wih[j][kx] = *(const short8*)(Bpack +
                ((size_t)((4 * w + j) * FB_NKC + FB_NKC_H + kx) * 64 + lane) * 8);

    short8 wreg[FB_KC_REG][4];
#pragma unroll
    for (int r = 0; r < FB_KC_REG; ++r)
#pragma unroll
        for (int j = 0; j < 4; ++j)
            wreg[r][j] = *(const short8*)(Bpack +
                ((size_t)((4 * w + j) * FB_NKC + FB_KC_LDS + r) * 64 + lane) * 8);

    const int xrow = tid >> 5;
    const int xc   = (tid & 31) * 4;
    const float* xbase = x + (size_t)(bb + xrow) * T_ * I_ + xc;
    float4 xreg = *(const float4*)(xbase);

    __syncthreads();

    f32x4 acc[4];
    short8 sb[3][4];

    for (int t = 0; t < T_; ++t) {
#pragma unroll
        for (int s = 0; s < 3; ++s)
#pragma unroll
            for (int j = 0; j < 4; ++j)
                sb[s][j] = *(const short8*)(Bpack +
                    ((size_t)((4 * w + j) * FB_NKC + FB_KC_LDS + FB_KC_REG + s) * 64 + lane) * 8);

        {
            ushort4 xs;
            xs.x = f2bf(xreg.x); xs.y = f2bf(xreg.y);
            xs.z = f2bf(xreg.z); xs.w = f2bf(xreg.w);
            *(ushort4*)&a_lds[xrow * FB_RS + H_ + xc] = xs;
        }
        __syncthreads();

        if (t + 1 < T_)
            xreg = *(const float4*)(xbase + (size_t)(t + 1) * I_);

#pragma unroll
        for (int j = 0; j < 4; ++j) acc[j] = (f32x4)(0.0f);

#pragma unroll
        for (int kc = 0; kc < FB_KC_LDS; ++kc) {
            short8 af = *(const short8*)&a_lds[mr * FB_RS + kc * 32 + q * 8];
#pragma unroll
            for (int j = 0; j < 4; ++j) {
                short8 bfr = *(const short8*)&w_lds[
                    (size_t)(((4 * w + j) * FB_KC_LDS + kc) * 64 + lane) * 8];
                acc[j] = __builtin_amdgcn_mfma_f32_16x16x32_bf16(af, bfr, acc[j], 0, 0, 0);
            }
        }
#pragma unroll
        for (int r = 0; r < FB_KC_REG; ++r) {
            short8 af = *(const short8*)&a_lds[mr * FB_RS + (FB_KC_LDS + r) * 32 + q * 8];
#pragma unroll
            for (int j = 0; j < 4; ++j)
                acc[j] = __builtin_amdgcn_mfma_f32_16x16x32_bf16(af, wreg[r][j], acc[j], 0, 0, 0);
        }
#pragma unroll
        for (int kx = 0; kx < 4; ++kx) {
            short8 af = *(const short8*)&a_lds[mr * FB_RS + H_ + kx * 32 + q * 8];
#pragma unroll
            for (int j = 0; j < 4; ++j)
                acc[j] = __builtin_amdgcn_mfma_f32_16x16x32_bf16(af, wih[j][kx], acc[j], 0, 0, 0);
        }
#pragma unroll
        for (int s = 0; s < FB_KC_STR; ++s) {
            int kc = FB_KC_LDS + FB_KC_REG + s;
            short8 af = *(const short8*)&a_lds[mr * FB_RS + kc * 32 + q * 8];
#pragma unroll
            for (int j = 0; j < 4; ++j)
                acc[j] = __builtin_amdgcn_mfma_f32_16x16x32_bf16(af, sb[s % 3][j], acc[j], 0, 0, 0);
            if (s + 3 < FB_KC_STR) {
#pragma unroll
                for (int j = 0; j < 4; ++j)
                    sb[s % 3][j] = *(const short8*)(Bpack +
                        ((size_t)((4 * w + j) * FB_NKC + kc + 3) * 64 + lane) * 8);
            }
        }
        __syncthreads();

#pragma unroll
        for (int j = 0; j < 4; ++j) {
            int col = (4 * w + j) * 16 + mr;
#pragma unroll
            for (int e = 0; e < 4; ++e) {
                float hv = fast_tanh(acc[j][e] + bias[j]);
                a_lds[(q * 4 + e) * FB_RS + col] = f2bf(hv);
            }
        }
    }
    __syncthreads();

    {
        const int row = tid >> 5;
        const int l32 = tid & 31;
        float s = 0.0f;
        for (int k = l32; k < H_; k += 32)
            s += bf2f(a_lds[row * FB_RS + k]) * fc_w[k];
#pragma unroll
        for (int off = 16; off > 0; off >>= 1)
            s += __shfl_down(s, off, 32);
        if (l32 == 0) out[bb + row] = s + fc_b[0];
    }
}

// ---------------------------------------------------------------------------

extern "C" void kernel_launch(void* const* d_in, const int* in_sizes, int n_in,
                              void* d_out, int out_size, void* d_ws, size_t ws_size,
                              hipStream_t stream) {
    const float* x    = (const float*)d_in[0];
    const float* W_ih = (const float*)d_in[1];
    const float* W_hh = (const float*)d_in[2];
    const float* b_ih = (const float*)d_in[3];
    const float* b_hh = (const float*)d_in[4];
    const float* fc_w = (const float*)d_in[5];
    const float* fc_b = (const float*)d_in[6];

    const size_t XP_OFF    = (size_t)32 * NKC * 64 * 8 * 2;            // 512 KB
    const size_t NEED_FAST = XP_OFF + (size_t)T_ * H_ * B_ * 4;        // +128 MB

    if (ws_size >= NEED_FAST) {
        unsigned short* Bpack = (unsigned short*)d_ws;
        float* xp = (float*)((char*)d_ws + XP_OFF);
        pack_w16<<<128, 256, 0, stream>>>(W_hh, Bpack);
        xproj_k<<<dim3(256, 4, 4), 256, 0, stream>>>(x, W_ih, b_ih, b_hh, xp);
        rnn_fast<<<16, 512, 0, stream>>>(Bpack, xp, fc_w, fc_b, (float*)d_out);
    } else {
        unsigned short* Bpack = (unsigned short*)d_ws;                 // 640 KB
        pack_w20<<<160, 256, 0, stream>>>(W_ih, W_hh, Bpack);
        rnn_fb<<<16, 512, 0, stream>>>(x, Bpack, b_ih, b_hh, fc_w, fc_b, (float*)d_out);
    }
}

// Round 3
// 890.877 us; speedup vs baseline: 1.3635x; 1.2486x over previous
//
#include <hip/hip_runtime.h>

// Elman RNN, B=256,T=256,I=128,H=512,O=1.
// v4: counters showed VGPR=128 -> compiler rematerialized "register" W loads,
//     making each step re-stream ~448 KB from L2 (= measured 8.4k cyc/step).
//     Now: KC_REG=13 kc pinned in VGPRs via asm "+v" (208 regs), KC_LDS=3 in
//     LDS, zero streamed; waves_per_eu(2,2) grants 256 VGPRs/wave; xp in bf16.
// Main loop: 16 blocks x 512 thr (8 waves, 1 block/CU), wave owns 64 h-cols.

#define B_   256
#define T_   256
#define I_   128
#define H_   512

typedef __attribute__((ext_vector_type(8))) short short8;
typedef __attribute__((ext_vector_type(4))) float f32x4;

static __device__ inline unsigned short f2bf(float f) {
    union { float f; unsigned u; } v; v.f = f;
    unsigned r = v.u + 0x7fffu + ((v.u >> 16) & 1u);   // RNE
    return (unsigned short)(r >> 16);
}
static __device__ inline float bf2f(unsigned short s) {
    union { unsigned u; float f; } v; v.u = ((unsigned)s) << 16;
    return v.f;
}
static __device__ inline float fast_tanh(float x) {
    float e = __expf(2.0f * x);
    return 1.0f - 2.0f / (e + 1.0f);
}

// ---------------------------------------------------------------------------
// FAST PATH (needs 512 KB + 64 MB workspace)
// ---------------------------------------------------------------------------
#define NKC   16   // K chunks of 32 covering W_hh (512)
#define RS2  520   // LDS h-row stride in bf16 elems (512 + 8 pad)
#define KC_LDS 3   // kc 0..2  in LDS (96 KB)
#define KC_REG 13  // kc 3..15 pinned in VGPRs (208 regs)

// Bpack[( (nt*NKC + kc)*64 + lane )*8 + e] = W_hh[n*H + k] as bf16
//   k = kc*32 + (lane>>4)*8 + e,  n = nt*16 + (lane&15)
__global__ void pack_w16(const float* __restrict__ W_hh,
                         unsigned short* __restrict__ Bpack) {
    int idx = blockIdx.x * blockDim.x + threadIdx.x;
    if (idx >= 32 * NKC * 64) return;
    int lane = idx & 63;
    int kc   = (idx >> 6) % NKC;
    int nt   = (idx >> 6) / NKC;
    int n  = nt * 16 + (lane & 15);
    int k0 = kc * 32 + (lane >> 4) * 8;
    unsigned short* dst = Bpack + (size_t)idx * 8;
#pragma unroll
    for (int e = 0; e < 8; ++e)
        dst[e] = f2bf(W_hh[n * H_ + k0 + e]);
}

// xp[t][n][b] = sum_i x[b][t][i] * W_ih[n][i] + b_ih[n] + b_hh[n]   (bf16)
__global__ __launch_bounds__(256)
void xproj_k(const float* __restrict__ x,
             const float* __restrict__ W_ih,
             const float* __restrict__ b_ih,
             const float* __restrict__ b_hh,
             unsigned short* __restrict__ xp) {
    const int tid  = threadIdx.x;
    const int lane = tid & 63;
    const int w    = tid >> 6;
    const int mr   = lane & 15;
    const int q    = lane >> 4;
    const int t    = blockIdx.x;
    const int ng   = blockIdx.y;            // 0..3
    const int bt   = blockIdx.z * 4 + w;    // 0..15

    // B fragments from x: col b = 16*bt+mr, k = i = kc*32 + q*8 + e
    short8 bf[4];
    const float* xb = x + ((size_t)(16 * bt + mr) * T_ + t) * I_ + q * 8;
#pragma unroll
    for (int kc = 0; kc < 4; ++kc) {
        float4 lo = *(const float4*)(xb + kc * 32);
        float4 hi = *(const float4*)(xb + kc * 32 + 4);
        short8 v;
        v[0] = (short)f2bf(lo.x); v[1] = (short)f2bf(lo.y);
        v[2] = (short)f2bf(lo.z); v[3] = (short)f2bf(lo.w);
        v[4] = (short)f2bf(hi.x); v[5] = (short)f2bf(hi.y);
        v[6] = (short)f2bf(hi.z); v[7] = (short)f2bf(hi.w);
        bf[kc] = v;
    }

    f32x4 acc[8];
#pragma unroll
    for (int j = 0; j < 8; ++j) acc[j] = (f32x4)(0.0f);

#pragma unroll
    for (int kc = 0; kc < 4; ++kc) {
#pragma unroll
        for (int j = 0; j < 8; ++j) {
            const float* ab = W_ih + (size_t)(ng * 128 + j * 16 + mr) * I_ + kc * 32 + q * 8;
            float4 lo = *(const float4*)(ab);
            float4 hi = *(const float4*)(ab + 4);
            short8 af;
            af[0] = (short)f2bf(lo.x); af[1] = (short)f2bf(lo.y);
            af[2] = (short)f2bf(lo.z); af[3] = (short)f2bf(lo.w);
            af[4] = (short)f2bf(hi.x); af[5] = (short)f2bf(hi.y);
            af[6] = (short)f2bf(hi.z); af[7] = (short)f2bf(hi.w);
            acc[j] = __builtin_amdgcn_mfma_f32_16x16x32_bf16(af, bf[kc], acc[j], 0, 0, 0);
        }
    }

    // D: col = b = 16*bt + mr, row = n_local = q*4 + e
#pragma unroll
    for (int j = 0; j < 8; ++j) {
#pragma unroll
        for (int e = 0; e < 4; ++e) {
            int n = ng * 128 + j * 16 + q * 4 + e;
            float bv = b_ih[n] + b_hh[n];
            xp[((size_t)t * H_ + n) * B_ + 16 * bt + mr] = f2bf(acc[j][e] + bv);
        }
    }
}

__global__ __launch_bounds__(512) __attribute__((amdgpu_waves_per_eu(2, 2)))
void rnn_fast(const unsigned short* __restrict__ Bpack,
              const unsigned short* __restrict__ xp,
              const float* __restrict__ fc_w,
              const float* __restrict__ fc_b,
              float* __restrict__ out) {
    __shared__ __align__(16) unsigned short a_lds[2][16 * RS2];            // 33.3 KB
    __shared__ __align__(16) unsigned short w_lds[32 * KC_LDS * 64 * 8];   // 96 KB

    const int tid  = threadIdx.x;
    const int lane = tid & 63;
    const int w    = tid >> 6;      // wave 0..7, owns cols [64w, 64w+64)
    const int q    = lane >> 4;     // 0..3
    const int mr   = lane & 15;
    const int bb   = blockIdx.x * 16;

    // h0 = 0
    for (int i = tid; i < 16 * RS2; i += 512) a_lds[0][i] = 0;

    // preload LDS-resident W chunks (kc 0..2), fragment layout
    for (int i = tid; i < 32 * KC_LDS * 64; i += 512) {
        int l  = i & 63;
        int kc = (i >> 6) % KC_LDS;
        int nt = (i >> 6) / KC_LDS;
        *(short8*)&w_lds[(size_t)i * 8] =
            *(const short8*)(Bpack + ((size_t)(nt * NKC + kc) * 64 + l) * 8);
    }

    // W_hh kc 3..15, pinned register-resident (208 VGPRs).
    short8 wreg[KC_REG][4];
#pragma unroll
    for (int r = 0; r < KC_REG; ++r)
#pragma unroll
        for (int j = 0; j < 4; ++j)
            wreg[r][j] = *(const short8*)(Bpack +
                ((size_t)((4 * w + j) * NKC + KC_LDS + r) * 64 + lane) * 8);
    // Opaque def: compiler cannot rematerialize the loads; values must live
    // in registers across the T-loop.
#pragma unroll
    for (int r = 0; r < KC_REG; ++r)
#pragma unroll
        for (int j = 0; j < 4; ++j)
            asm volatile("" : "+v"(wreg[r][j]));

    __syncthreads();  // a_lds[0] zeros + w_lds visible

    f32x4 acc[4];
    const unsigned short* xpt = xp + (size_t)0;

    for (int t = 0; t < T_; ++t) {
        const unsigned short* A = a_lds[t & 1];
        unsigned short* An      = a_lds[(t & 1) ^ 1];

        // xp prefetch for this step's epilogue (bf16, 8B per j)
        ushort4 xpr[4];
#pragma unroll
        for (int j = 0; j < 4; ++j) {
            int col = (4 * w + j) * 16 + mr;
            xpr[j] = *(const ushort4*)(xpt + ((size_t)col) * B_ + bb + 4 * q);
        }

#pragma unroll
        for (int j = 0; j < 4; ++j) acc[j] = (f32x4)(0.0f);

        // --- LDS-resident kcs (0..2) ---
#pragma unroll
        for (int kc = 0; kc < KC_LDS; ++kc) {
            short8 af = *(const short8*)&A[mr * RS2 + kc * 32 + q * 8];
#pragma unroll
            for (int j = 0; j < 4; ++j) {
                short8 bfr = *(const short8*)&w_lds[
                    (size_t)(((4 * w + j) * KC_LDS + kc) * 64 + lane) * 8];
                acc[j] = __builtin_amdgcn_mfma_f32_16x16x32_bf16(af, bfr, acc[j], 0, 0, 0);
            }
        }
        // --- register-resident kcs (3..15) ---
#pragma unroll
        for (int r = 0; r < KC_REG; ++r) {
            short8 af = *(const short8*)&A[mr * RS2 + (KC_LDS + r) * 32 + q * 8];
#pragma unroll
            for (int j = 0; j < 4; ++j)
                acc[j] = __builtin_amdgcn_mfma_f32_16x16x32_bf16(af, wreg[r][j], acc[j], 0, 0, 0);
        }

        // epilogue: h_{t+1} = tanh(acc + xp); D row m = q*4+e, col = (4w+j)*16+mr
#pragma unroll
        for (int j = 0; j < 4; ++j) {
            int col = (4 * w + j) * 16 + mr;
#pragma unroll
            for (int e = 0; e < 4; ++e) {
                float hv = fast_tanh(acc[j][e] + bf2f(xpr[j][e]));
                An[(q * 4 + e) * RS2 + col] = f2bf(hv);
            }
        }
        xpt += (size_t)H_ * B_;
        __syncthreads();   // h_{t+1} visible; fences A reads vs next overwrite
    }

    // out[b] = h_T[b] . fc_w + fc_b  (32 threads per batch row); h_T in buf 0 (T even)
    {
        const int row = tid >> 5;
        const int l32 = tid & 31;
        float s = 0.0f;
        for (int k = l32; k < H_; k += 32)
            s += bf2f(a_lds[0][row * RS2 + k]) * fc_w[k];
#pragma unroll
        for (int off = 16; off > 0; off >>= 1)
            s += __shfl_down(s, off, 32);
        if (l32 == 0) out[bb + row] = s + fc_b[0];
    }
}

// ---------------------------------------------------------------------------
// FALLBACK PATH — round-0 kernel verbatim (640 KB workspace, measured 1214 µs)
// ---------------------------------------------------------------------------
#define FB_NKC   20
#define FB_NKC_H 16
#define FB_RS   648
#define FB_KC_LDS 4
#define FB_KC_REG 5
#define FB_KC_STR 7

__global__ void pack_w20(const float* __restrict__ W_ih,
                         const float* __restrict__ W_hh,
                         unsigned short* __restrict__ Bpack) {
    int idx = blockIdx.x * blockDim.x + threadIdx.x;
    if (idx >= 32 * FB_NKC * 64) return;
    int lane = idx & 63;
    int kc   = (idx >> 6) % FB_NKC;
    int nt   = (idx >> 6) / FB_NKC;
    int n  = nt * 16 + (lane & 15);
    int k0 = kc * 32 + (lane >> 4) * 8;
    unsigned short* dst = Bpack + (size_t)idx * 8;
#pragma unroll
    for (int e = 0; e < 8; ++e) {
        int k = k0 + e;
        float v = (k < H_) ? W_hh[n * H_ + k] : W_ih[n * I_ + (k - H_)];
        dst[e] = f2bf(v);
    }
}

__global__ __launch_bounds__(512, 2)
void rnn_fb(const float* __restrict__ x,
            const unsigned short* __restrict__ Bpack,
            const float* __restrict__ b_ih,
            const float* __restrict__ b_hh,
            const float* __restrict__ fc_w,
            const float* __restrict__ fc_b,
            float* __restrict__ out) {
    __shared__ __align__(16) unsigned short a_lds[16 * FB_RS];
    __shared__ __align__(16) unsigned short w_lds[32 * FB_KC_LDS * 64 * 8];

    const int tid  = threadIdx.x;
    const int lane = tid & 63;
    const int w    = tid >> 6;
    const int q    = lane >> 4;
    const int mr   = lane & 15;
    const int bb   = blockIdx.x * 16;

    for (int i = tid; i < 16 * FB_RS; i += 512) a_lds[i] = 0;

    for (int i = tid; i < 32 * FB_KC_LDS * 64; i += 512) {
        int l  = i & 63;
        int kc = (i >> 6) & (FB_KC_LDS - 1);
        int nt = i >> 8;
        *(short8*)&w_lds[(size_t)i * 8] =
            *(const short8*)(Bpack + ((size_t)(nt * FB_NKC + kc) * 64 + l) * 8);
    }

    float bias[4];
#pragma unroll
    for (int j = 0; j < 4; ++j) {
        int col = (4 * w + j) * 16 + mr;
        bias[j] = b_ih[col] + b_hh[col];
    }

    short8 wih[4][4];
#pragma unroll
    for (int j = 0; j < 4; ++j)
#pragma unroll
        for (int kx = 0; kx < 4; ++kx)
            wih[j][kx] = *(const short8*)(Bpack +
                ((size_t)((4 * w + j) * FB_NKC + FB_NKC_H + kx) * 64 + lane) * 8);

    short8 wreg[FB_KC_REG][4];
#pragma unroll
    for (int r = 0; r < FB_KC_REG; ++r)
#pragma unroll
        for (int j = 0; j < 4; ++j)
            wreg[r][j] = *(const short8*)(Bpack +
                ((size_t)((4 * w + j) * FB_NKC + FB_KC_LDS + r) * 64 + lane) * 8);

    const int xrow = tid >> 5;
    const int xc   = (tid & 31) * 4;
    const float* xbase = x + (size_t)(bb + xrow) * T_ * I_ + xc;
    float4 xreg = *(const float4*)(xbase);

    __syncthreads();

    f32x4 acc[4];
    short8 sb[3][4];

    for (int t = 0; t < T_; ++t) {
#pragma unroll
        for (int s = 0; s < 3; ++s)
#pragma unroll
            for (int j = 0; j < 4; ++j)
                sb[s][j] = *(const short8*)(Bpack +
                    ((size_t)((4 * w + j) * FB_NKC + FB_KC_LDS + FB_KC_REG + s) * 64 + lane) * 8);

        {
            ushort4 xs;
            xs.x = f2bf(xreg.x); xs.y = f2bf(xreg.y);
            xs.z = f2bf(xreg.z); xs.w = f2bf(xreg.w);
            *(ushort4*)&a_lds[xrow * FB_RS + H_ + xc] = xs;
        }
        __syncthreads();

        if (t + 1 < T_)
            xreg = *(const float4*)(xbase + (size_t)(t + 1) * I_);

#pragma unroll
        for (int j = 0; j < 4; ++j) acc[j] = (f32x4)(0.0f);

#pragma unroll
        for (int kc = 0; kc < FB_KC_LDS; ++kc) {
            short8 af = *(const short8*)&a_lds[mr * FB_RS + kc * 32 + q * 8];
#pragma unroll
            for (int j = 0; j < 4; ++j) {
                short8 bfr = *(const short8*)&w_lds[
                    (size_t)(((4 * w + j) * FB_KC_LDS + kc) * 64 + lane) * 8];
                acc[j] = __builtin_amdgcn_mfma_f32_16x16x32_bf16(af, bfr, acc[j], 0, 0, 0);
            }
        }
#pragma unroll
        for (int r = 0; r < FB_KC_REG; ++r) {
            short8 af = *(const short8*)&a_lds[mr * FB_RS + (FB_KC_LDS + r) * 32 + q * 8];
#pragma unroll
            for (int j = 0; j < 4; ++j)
                acc[j] = __builtin_amdgcn_mfma_f32_16x16x32_bf16(af, wreg[r][j], acc[j], 0, 0, 0);
        }
#pragma unroll
        for (int kx = 0; kx < 4; ++kx) {
            short8 af = *(const short8*)&a_lds[mr * FB_RS + H_ + kx * 32 + q * 8];
#pragma unroll
            for (int j = 0; j < 4; ++j)
                acc[j] = __builtin_amdgcn_mfma_f32_16x16x32_bf16(af, wih[j][kx], acc[j], 0, 0, 0);
        }
#pragma unroll
        for (int s = 0; s < FB_KC_STR; ++s) {
            int kc = FB_KC_LDS + FB_KC_REG + s;
            short8 af = *(const short8*)&a_lds[mr * FB_RS + kc * 32 + q * 8];
#pragma unroll
            for (int j = 0; j < 4; ++j)
                acc[j] = __builtin_amdgcn_mfma_f32_16x16x32_bf16(af, sb[s % 3][j], acc[j], 0, 0, 0);
            if (s + 3 < FB_KC_STR) {
#pragma unroll
                for (int j = 0; j < 4; ++j)
                    sb[s % 3][j] = *(const short8*)(Bpack +
                        ((size_t)((4 * w + j) * FB_NKC + kc + 3) * 64 + lane) * 8);
            }
        }
        __syncthreads();

#pragma unroll
        for (int j = 0; j < 4; ++j) {
            int col = (4 * w + j) * 16 + mr;
#pragma unroll
            for (int e = 0; e < 4; ++e) {
                float hv = fast_tanh(acc[j][e] + bias[j]);
                a_lds[(q * 4 + e) * FB_RS + col] = f2bf(hv);
            }
        }
    }
    __syncthreads();

    {
        const int row = tid >> 5;
        const int l32 = tid & 31;
        float s = 0.0f;
        for (int k = l32; k < H_; k += 32)
            s += bf2f(a_lds[row * FB_RS + k]) * fc_w[k];
#pragma unroll
        for (int off = 16; off > 0; off >>= 1)
            s += __shfl_down(s, off, 32);
        if (l32 == 0) out[bb + row] = s + fc_b[0];
    }
}

// ---------------------------------------------------------------------------

extern "C" void kernel_launch(void* const* d_in, const int* in_sizes, int n_in,
                              void* d_out, int out_size, void* d_ws, size_t ws_size,
                              hipStream_t stream) {
    const float* x    = (const float*)d_in[0];
    const float* W_ih = (const float*)d_in[1];
    const float* W_hh = (const float*)d_in[2];
    const float* b_ih = (const float*)d_in[3];
    const float* b_hh = (const float*)d_in[4];
    const float* fc_w = (const float*)d_in[5];
    const float* fc_b = (const float*)d_in[6];

    const size_t XP_OFF    = (size_t)32 * NKC * 64 * 8 * 2;            // 512 KB
    const size_t NEED_FAST = XP_OFF + (size_t)T_ * H_ * B_ * 2;        // +64 MB (bf16)

    if (ws_size >= NEED_FAST) {
        unsigned short* Bpack = (unsigned short*)d_ws;
        unsigned short* xp = (unsigned short*)((char*)d_ws + XP_OFF);
        pack_w16<<<128, 256, 0, stream>>>(W_hh, Bpack);
        xproj_k<<<dim3(256, 4, 4), 256, 0, stream>>>(x, W_ih, b_ih, b_hh, xp);
        rnn_fast<<<16, 512, 0, stream>>>(Bpack, xp, fc_w, fc_b, (float*)d_out);
    } else {
        unsigned short* Bpack = (unsigned short*)d_ws;                 // 640 KB
        pack_w20<<<160, 256, 0, stream>>>(W_ih, W_hh, Bpack);
        rnn_fb<<<16, 512, 0, stream>>>(x, Bpack, b_ih, b_hh, fc_w, fc_b, (float*)d_out);
    }
}

// Round 5
// 840.780 us; speedup vs baseline: 1.4447x; 1.0596x over previous
//
#include <hip/hip_runtime.h>

// Elman RNN, B=256,T=256,I=128,H=512,O=1.
// v6 = v5 structure with all v_cvt_pk_bf16_f32 removed (suspected non-RNE
//      rounding biased the recurrent h path; accumulated over 256 steps ->
//      absmax 0.24). All bf16 packing back to explicit RNE f2bf, making the
//      h recursion bitwise identical to v4 (passed, 0.0078).
// Kept from v5: dense per-block xp layout [t][bg][n][16b] (no HBM over-fetch),
//      contiguous-tile xproj, KC_REG=7 real residency + 6 streamed kc.
// Main loop: 16 blocks x 512 thr (8 waves, 1 block/CU), wave owns 64 h-cols.

#define B_   256
#define T_   256
#define I_   128
#define H_   512

typedef __attribute__((ext_vector_type(8))) short short8;
typedef __attribute__((ext_vector_type(4))) float f32x4;

static __device__ inline unsigned short f2bf(float f) {
    union { float f; unsigned u; } v; v.f = f;
    unsigned r = v.u + 0x7fffu + ((v.u >> 16) & 1u);   // RNE
    return (unsigned short)(r >> 16);
}
static __device__ inline float bf2f(unsigned short s) {
    union { unsigned u; float f; } v; v.u = ((unsigned)s) << 16;
    return v.f;
}
static __device__ inline float fast_tanh(float x) {
    float e = __expf(2.0f * x);
    return 1.0f - 2.0f / (e + 1.0f);
}
static __device__ inline short8 pack8(float4 lo, float4 hi) {
    short8 v;
    v[0] = (short)f2bf(lo.x); v[1] = (short)f2bf(lo.y);
    v[2] = (short)f2bf(lo.z); v[3] = (short)f2bf(lo.w);
    v[4] = (short)f2bf(hi.x); v[5] = (short)f2bf(hi.y);
    v[6] = (short)f2bf(hi.z); v[7] = (short)f2bf(hi.w);
    return v;
}

// ---------------------------------------------------------------------------
// FAST PATH (needs 512 KB + 64 MB workspace)
// ---------------------------------------------------------------------------
#define NKC   16   // K chunks of 32 covering W_hh (512)
#define RS2  520   // LDS h-row stride in bf16 elems (512 + 8 pad)
#define KC_LDS 3   // kc 0..2  in LDS (96 KB)
#define KC_REG 7   // kc 3..9  pinned in VGPRs (112 regs)
#define KC_STR 6   // kc 10..15 streamed from L2, 4-buf rolling prefetch

// Bpack[( (nt*NKC + kc)*64 + lane )*8 + e] = W_hh[n*H + k] as bf16
//   k = kc*32 + (lane>>4)*8 + e,  n = nt*16 + (lane&15)
__global__ void pack_w16(const float* __restrict__ W_hh,
                         unsigned short* __restrict__ Bpack) {
    int idx = blockIdx.x * blockDim.x + threadIdx.x;
    if (idx >= 32 * NKC * 64) return;
    int lane = idx & 63;
    int kc   = (idx >> 6) % NKC;
    int nt   = (idx >> 6) / NKC;
    int n  = nt * 16 + (lane & 15);
    int k0 = kc * 32 + (lane >> 4) * 8;
    unsigned short* dst = Bpack + (size_t)idx * 8;
#pragma unroll
    for (int e = 0; e < 8; ++e)
        dst[e] = f2bf(W_hh[n * H_ + k0 + e]);
}

// xp[((t*16+bg)*512 + n)*16 + bl] = bf16( W_ih[n]·x[16bg+bl][t] + b_ih[n]+b_hh[n] )
// grid (T_, 16), block 256 (4 waves). Wave w owns n rows [128w, 128w+128).
// Block output = contiguous 16 KB tile.
__global__ __launch_bounds__(256)
void xproj_k(const float* __restrict__ x,
             const float* __restrict__ W_ih,
             const float* __restrict__ b_ih,
             const float* __restrict__ b_hh,
             unsigned short* __restrict__ xp) {
    const int tid  = threadIdx.x;
    const int lane = tid & 63;
    const int w    = tid >> 6;      // 0..3
    const int mr   = lane & 15;
    const int q    = lane >> 4;
    const int t    = blockIdx.x;
    const int bg   = blockIdx.y;    // 0..15

    // B fragments from x: col b-local = mr, k = i = kc*32 + q*8 + e
    short8 bf[4];
    const float* xb = x + ((size_t)(16 * bg + mr) * T_ + t) * I_ + q * 8;
#pragma unroll
    for (int kc = 0; kc < 4; ++kc)
        bf[kc] = pack8(*(const float4*)(xb + kc * 32),
                       *(const float4*)(xb + kc * 32 + 4));

    unsigned short* dst = xp + ((size_t)(t * 16 + bg) * 512) * 16;

#pragma unroll
    for (int mt = 0; mt < 8; ++mt) {
        const int nrow = w * 128 + mt * 16 + mr;     // A row for this lane
        f32x4 a = (f32x4)(0.0f);
#pragma unroll
        for (int kc = 0; kc < 4; ++kc) {
            const float* ab = W_ih + (size_t)nrow * I_ + kc * 32 + q * 8;
            short8 af = pack8(*(const float4*)(ab), *(const float4*)(ab + 4));
            a = __builtin_amdgcn_mfma_f32_16x16x32_bf16(af, bf[kc], a, 0, 0, 0);
        }
        // D: row n-local = q*4+e, col b-local = mr
#pragma unroll
        for (int e = 0; e < 4; ++e) {
            int n = w * 128 + mt * 16 + q * 4 + e;
            float bv = b_ih[n] + b_hh[n];
            dst[(size_t)n * 16 + mr] = f2bf(a[e] + bv);
        }
    }
}

__global__ __launch_bounds__(512) __attribute__((amdgpu_waves_per_eu(2, 2)))
void rnn_fast(const unsigned short* __restrict__ Bpack,
              const unsigned short* __restrict__ xp,
              const float* __restrict__ fc_w,
              const float* __restrict__ fc_b,
              float* __restrict__ out) {
    __shared__ __align__(16) unsigned short a_lds[2][16 * RS2];            // 33.3 KB
    __shared__ __align__(16) unsigned short w_lds[32 * KC_LDS * 64 * 8];   // 96 KB

    const int tid  = threadIdx.x;
    const int lane = tid & 63;
    const int w    = tid >> 6;      // wave 0..7, owns cols [64w, 64w+64)
    const int q    = lane >> 4;     // 0..3
    const int mr   = lane & 15;
    const int blk  = blockIdx.x;    // batch group
    const int bb   = blk * 16;

    // h0 = 0
    for (int i = tid; i < 16 * RS2; i += 512) a_lds[0][i] = 0;

    // preload LDS-resident W chunks (kc 0..2), fragment layout
    for (int i = tid; i < 32 * KC_LDS * 64; i += 512) {
        int l  = i & 63;
        int kc = (i >> 6) % KC_LDS;
        int nt = (i >> 6) / KC_LDS;
        *(short8*)&w_lds[(size_t)i * 8] =
            *(const short8*)(Bpack + ((size_t)(nt * NKC + kc) * 64 + l) * 8);
    }

    // W_hh kc 3..9, pinned register-resident (112 VGPRs)
    short8 wreg[KC_REG][4];
#pragma unroll
    for (int r = 0; r < KC_REG; ++r)
#pragma unroll
        for (int j = 0; j < 4; ++j)
            wreg[r][j] = *(const short8*)(Bpack +
                ((size_t)((4 * w + j) * NKC + KC_LDS + r) * 64 + lane) * 8);
#pragma unroll
    for (int r = 0; r < KC_REG; ++r)
#pragma unroll
        for (int j = 0; j < 4; ++j)
            asm volatile("" : "+v"(wreg[r][j]));

    __syncthreads();  // a_lds[0] zeros + w_lds visible

    f32x4 acc[4];
    short8 sb[4][4];   // streamed prefetch buffers (4 kc in flight)

    // dense xp: block's tile for step t starts at (t*16+blk)*512*16 elems
    const unsigned short* xpt = xp + ((size_t)blk * 512) * 16;
    const size_t xstride = (size_t)16 * 512 * 16;   // per-t elems

    for (int t = 0; t < T_; ++t) {
        const unsigned short* A = a_lds[t & 1];
        unsigned short* An      = a_lds[(t & 1) ^ 1];

        // streamed W issue: kc 10..13 into sb[0..3]
#pragma unroll
        for (int s = 0; s < 4; ++s)
#pragma unroll
            for (int j = 0; j < 4; ++j)
                sb[s][j] = *(const short8*)(Bpack +
                    ((size_t)((4 * w + j) * NKC + KC_LDS + KC_REG + s) * 64 + lane) * 8);

        // xp prefetch (dense: contiguous 512B per wave per j), consumed in epilogue
        ushort4 xpr[4];
#pragma unroll
        for (int j = 0; j < 4; ++j) {
            int col = (4 * w + j) * 16 + mr;
            xpr[j] = *(const ushort4*)(xpt + (size_t)col * 16 + q * 4);
        }

#pragma unroll
        for (int j = 0; j < 4; ++j) acc[j] = (f32x4)(0.0f);

        // --- LDS-resident kcs (0..2) ---
#pragma unroll
        for (int kc = 0; kc < KC_LDS; ++kc) {
            short8 af = *(const short8*)&A[mr * RS2 + kc * 32 + q * 8];
#pragma unroll
            for (int j = 0; j < 4; ++j) {
                short8 bfr = *(const short8*)&w_lds[
                    (size_t)(((4 * w + j) * KC_LDS + kc) * 64 + lane) * 8];
                acc[j] = __builtin_amdgcn_mfma_f32_16x16x32_bf16(af, bfr, acc[j], 0, 0, 0);
            }
        }
        // --- register-resident kcs (3..9) ---
#pragma unroll
        for (int r = 0; r < KC_REG; ++r) {
            short8 af = *(const short8*)&A[mr * RS2 + (KC_LDS + r) * 32 + q * 8];
#pragma unroll
            for (int j = 0; j < 4; ++j)
                acc[j] = __builtin_amdgcn_mfma_f32_16x16x32_bf16(af, wreg[r][j], acc[j], 0, 0, 0);
        }
        // --- streamed kcs (10..15), rolling refill of sb[0],sb[1] ---
#pragma unroll
        for (int s = 0; s < KC_STR; ++s) {
            int kc = KC_LDS + KC_REG + s;
            short8 af = *(const short8*)&A[mr * RS2 + kc * 32 + q * 8];
#pragma unroll
            for (int j = 0; j < 4; ++j)
                acc[j] = __builtin_amdgcn_mfma_f32_16x16x32_bf16(af, sb[s & 3][j], acc[j], 0, 0, 0);
            if (s + 4 < KC_STR) {
#pragma unroll
                for (int j = 0; j < 4; ++j)
                    sb[s & 3][j] = *(const short8*)(Bpack +
                        ((size_t)((4 * w + j) * NKC + kc + 4) * 64 + lane) * 8);
            }
        }

        // epilogue: h_{t+1} = tanh(acc + xp); D row m = q*4+e, col = (4w+j)*16+mr
#pragma unroll
        for (int j = 0; j < 4; ++j) {
            int col = (4 * w + j) * 16 + mr;
            const unsigned short* xj = (const unsigned short*)&xpr[j];
#pragma unroll
            for (int e = 0; e < 4; ++e) {
                float hv = fast_tanh(acc[j][e] + bf2f(xj[e]));
                An[(q * 4 + e) * RS2 + col] = f2bf(hv);
            }
        }
        xpt += xstride;
        __syncthreads();   // h_{t+1} visible; fences A reads vs next overwrite
    }

    // out[b] = h_T[b] . fc_w + fc_b  (32 threads per batch row); h_T in buf 0 (T even)
    {
        const int row = tid >> 5;
        const int l32 = tid & 31;
        float s = 0.0f;
        for (int k = l32; k < H_; k += 32)
            s += bf2f(a_lds[0][row * RS2 + k]) * fc_w[k];
#pragma unroll
        for (int off = 16; off > 0; off >>= 1)
            s += __shfl_down(s, off, 32);
        if (l32 == 0) out[bb + row] = s + fc_b[0];
    }
}

// ---------------------------------------------------------------------------
// FALLBACK PATH — round-0 kernel verbatim (640 KB workspace, measured 1214 µs)
// ---------------------------------------------------------------------------
#define FB_NKC   20
#define FB_NKC_H 16
#define FB_RS   648
#define FB_KC_LDS 4
#define FB_KC_REG 5
#define FB_KC_STR 7

__global__ void pack_w20(const float* __restrict__ W_ih,
                         const float* __restrict__ W_hh,
                         unsigned short* __restrict__ Bpack) {
    int idx = blockIdx.x * blockDim.x + threadIdx.x;
    if (idx >= 32 * FB_NKC * 64) return;
    int lane = idx & 63;
    int kc   = (idx >> 6) % FB_NKC;
    int nt   = (idx >> 6) / FB_NKC;
    int n  = nt * 16 + (lane & 15);
    int k0 = kc * 32 + (lane >> 4) * 8;
    unsigned short* dst = Bpack + (size_t)idx * 8;
#pragma unroll
    for (int e = 0; e < 8; ++e) {
        int k = k0 + e;
        float v = (k < H_) ? W_hh[n * H_ + k] : W_ih[n * I_ + (k - H_)];
        dst[e] = f2bf(v);
    }
}

__global__ __launch_bounds__(512, 2)
void rnn_fb(const float* __restrict__ x,
            const unsigned short* __restrict__ Bpack,
            const float* __restrict__ b_ih,
            const float* __restrict__ b_hh,
            const float* __restrict__ fc_w,
            const float* __restrict__ fc_b,
            float* __restrict__ out) {
    __shared__ __align__(16) unsigned short a_lds[16 * FB_RS];
    __shared__ __align__(16) unsigned short w_lds[32 * FB_KC_LDS * 64 * 8];

    const int tid  = threadIdx.x;
    const int lane = tid & 63;
    const int w    = tid >> 6;
    const int q    = lane >> 4;
    const int mr   = lane & 15;
    const int bb   = blockIdx.x * 16;

    for (int i = tid; i < 16 * FB_RS; i += 512) a_lds[i] = 0;

    for (int i = tid; i < 32 * FB_KC_LDS * 64; i += 512) {
        int l  = i & 63;
        int kc = (i >> 6) & (FB_KC_LDS - 1);
        int nt = i >> 8;
        *(short8*)&w_lds[(size_t)i * 8] =
            *(const short8*)(Bpack + ((size_t)(nt * FB_NKC + kc) * 64 + l) * 8);
    }

    float bias[4];
#pragma unroll
    for (int j = 0; j < 4; ++j) {
        int col = (4 * w + j) * 16 + mr;
        bias[j] = b_ih[col] + b_hh[col];
    }

    short8 wih[4][4];
#pragma unroll
    for (int j = 0; j < 4; ++j)
#pragma unroll
        for (int kx = 0; kx < 4; ++kx)
            wih[j][kx] = *(const short8*)(Bpack +
                ((size_t)((4 * w + j) * FB_NKC + FB_NKC_H + kx) * 64 + lane) * 8);

    short8 wreg[FB_KC_REG][4];
#pragma unroll
    for (int r = 0; r < FB_KC_REG; ++r)
#pragma unroll
        for (int j = 0; j < 4; ++j)
            wreg[r][j] = *(const short8*)(Bpack +
                ((size_t)((4 * w + j) * FB_NKC + FB_KC_LDS + r) * 64 + lane) * 8);

    const int xrow = tid >> 5;
    const int xc   = (tid & 31) * 4;
    const float* xbase = x + (size_t)(bb + xrow) * T_ * I_ + xc;
    float4 xreg = *(const float4*)(xbase);

    __syncthreads();

    f32x4 acc[4];
    short8 sb[3][4];

    for (int t = 0; t < T_; ++t) {
#pragma unroll
        for (int s = 0; s < 3; ++s)
#pragma unroll
            for (int j = 0; j < 4; ++j)
                sb[s][j] = *(const short8*)(Bpack +
                    ((size_t)((4 * w + j) * FB_NKC + FB_KC_LDS + FB_KC_REG + s) * 64 + lane) * 8);

        {
            ushort4 xs;
            xs.x = f2bf(xreg.x); xs.y = f2bf(xreg.y);
            xs.z = f2bf(xreg.z); xs.w = f2bf(xreg.w);
            *(ushort4*)&a_lds[xrow * FB_RS + H_ + xc] = xs;
        }
        __syncthreads();

        if (t + 1 < T_)
            xreg = *(const float4*)(xbase + (size_t)(t + 1) * I_);

#pragma unroll
        for (int j = 0; j < 4; ++j) acc[j] = (f32x4)(0.0f);

#pragma unroll
        for (int kc = 0; kc < FB_KC_LDS; ++kc) {
            short8 af = *(const short8*)&a_lds[mr * FB_RS + kc * 32 + q * 8];
#pragma unroll
            for (int j = 0; j < 4; ++j) {
                short8 bfr = *(const short8*)&w_lds[
                    (size_t)(((4 * w + j) * FB_KC_LDS + kc) * 64 + lane) * 8];
                acc[j] = __builtin_amdgcn_mfma_f32_16x16x32_bf16(af, bfr, acc[j], 0, 0, 0);
            }
        }
#pragma unroll
        for (int r = 0; r < FB_KC_REG; ++r) {
            short8 af = *(const short8*)&a_lds[mr * FB_RS + (FB_KC_LDS + r) * 32 + q * 8];
#pragma unroll
            for (int j = 0; j < 4; ++j)
                acc[j] = __builtin_amdgcn_mfma_f32_16x16x32_bf16(af, wreg[r][j], acc[j], 0, 0, 0);
        }
#pragma unroll
        for (int kx = 0; kx < 4; ++kx) {
            short8 af = *(const short8*)&a_lds[mr * FB_RS + H_ + kx * 32 + q * 8];
#pragma unroll
            for (int j = 0; j < 4; ++j)
                acc[j] = __builtin_amdgcn_mfma_f32_16x16x32_bf16(af, wih[j][kx], acc[j], 0, 0, 0);
        }
#pragma unroll
        for (int s = 0; s < FB_KC_STR; ++s) {
            int kc = FB_KC_LDS + FB_KC_REG + s;
            short8 af = *(const short8*)&a_lds[mr * FB_RS + kc * 32 + q * 8];
#pragma unroll
            for (int j = 0; j < 4; ++j)
                acc[j] = __builtin_amdgcn_mfma_f32_16x16x32_bf16(af, sb[s % 3][j], acc[j], 0, 0, 0);
            if (s + 3 < FB_KC_STR) {
#pragma unroll
                for (int j = 0; j < 4; ++j)
                    sb[s % 3][j] = *(const short8*)(Bpack +
                        ((size_t)((4 * w + j) * FB_NKC + kc + 3) * 64 + lane) * 8);
            }
        }
        __syncthreads();

#pragma unroll
        for (int j = 0; j < 4; ++j) {
            int col = (4 * w + j) * 16 + mr;
#pragma unroll
            for (int e = 0; e < 4; ++e) {
                float hv = fast_tanh(acc[j][e] + bias[j]);
                a_lds[(q * 4 + e) * FB_RS + col] = f2bf(hv);
            }
        }
    }
    __syncthreads();

    {
        const int row = tid >> 5;
        const int l32 = tid & 31;
        float s = 0.0f;
        for (int k = l32; k < H_; k += 32)
            s += bf2f(a_lds[row * FB_RS + k]) * fc_w[k];
#pragma unroll
        for (int off = 16; off > 0; off >>= 1)
            s += __shfl_down(s, off, 32);
        if (l32 == 0) out[bb + row] = s + fc_b[0];
    }
}

// ---------------------------------------------------------------------------

extern "C" void kernel_launch(void* const* d_in, const int* in_sizes, int n_in,
                              void* d_out, int out_size, void* d_ws, size_t ws_size,
                              hipStream_t stream) {
    const float* x    = (const float*)d_in[0];
    const float* W_ih = (const float*)d_in[1];
    const float* W_hh = (const float*)d_in[2];
    const float* b_ih = (const float*)d_in[3];
    const float* b_hh = (const float*)d_in[4];
    const float* fc_w = (const float*)d_in[5];
    const float* fc_b = (const float*)d_in[6];

    const size_t XP_OFF    = (size_t)32 * NKC * 64 * 8 * 2;            // 512 KB
    const size_t NEED_FAST = XP_OFF + (size_t)T_ * H_ * B_ * 2;        // +64 MB (bf16)

    if (ws_size >= NEED_FAST) {
        unsigned short* Bpack = (unsigned short*)d_ws;
        unsigned short* xp = (unsigned short*)((char*)d_ws + XP_OFF);
        pack_w16<<<128, 256, 0, stream>>>(W_hh, Bpack);
        xproj_k<<<dim3(T_, 16), 256, 0, stream>>>(x, W_ih, b_ih, b_hh, xp);
        rnn_fast<<<16, 512, 0, stream>>>(Bpack, xp, fc_w, fc_b, (float*)d_out);
    } else {
        unsigned short* Bpack = (unsigned short*)d_ws;                 // 640 KB
        pack_w20<<<160, 256, 0, stream>>>(W_ih, W_hh, Bpack);
        rnn_fb<<<16, 512, 0, stream>>>(x, Bpack, b_ih, b_hh, fc_w, fc_b, (float*)d_out);
    }
}

// Round 6
// 649.700 us; speedup vs baseline: 1.8696x; 1.2941x over previous
//
#include <hip/hip_runtime.h>

// Elman RNN, B=256,T=256,I=128,H=512,O=1.
// v7: v6 counters showed VGPR=128 == wreg(112)+acc(16) exactly -> everything
//     else (sb bufs, addresses) spilled/rematerialized per step = the 57%
//     VALUBusy. Fix: fit the 128-reg cap honestly. KC_REG=3 (48 pinned),
//     KC_STR=10 (3-deep rolling from L2), leaving ~64 regs for sb/addr.
//     Plus: rcp-based tanh (no IEEE div sequence), 4-t-batched xproj.
// Main loop: 16 blocks x 512 thr (8 waves, 1 block/CU), wave owns 64 h-cols.

#define B_   256
#define T_   256
#define I_   128
#define H_   512

typedef __attribute__((ext_vector_type(8))) short short8;
typedef __attribute__((ext_vector_type(4))) float f32x4;

static __device__ inline unsigned short f2bf(float f) {
    union { float f; unsigned u; } v; v.f = f;
    unsigned r = v.u + 0x7fffu + ((v.u >> 16) & 1u);   // RNE
    return (unsigned short)(r >> 16);
}
static __device__ inline float bf2f(unsigned short s) {
    union { unsigned u; float f; } v; v.u = ((unsigned)s) << 16;
    return v.f;
}
// tanh(x) = 1 - 2/(e^{2x}+1); raw v_rcp (~1 ulp f32) instead of IEEE div.
static __device__ inline float fast_tanh(float x) {
    float e = __expf(2.0f * x);
    float r = __builtin_amdgcn_rcpf(e + 1.0f);
    return __builtin_fmaf(-2.0f, r, 1.0f);
}
static __device__ inline short8 pack8(float4 lo, float4 hi) {
    short8 v;
    v[0] = (short)f2bf(lo.x); v[1] = (short)f2bf(lo.y);
    v[2] = (short)f2bf(lo.z); v[3] = (short)f2bf(lo.w);
    v[4] = (short)f2bf(hi.x); v[5] = (short)f2bf(hi.y);
    v[6] = (short)f2bf(hi.z); v[7] = (short)f2bf(hi.w);
    return v;
}

// ---------------------------------------------------------------------------
// FAST PATH (needs 512 KB + 64 MB workspace)
// ---------------------------------------------------------------------------
#define NKC   16   // K chunks of 32 covering W_hh (512)
#define RS2  520   // LDS h-row stride in bf16 elems (512 + 8 pad)
#define KC_LDS 3   // kc 0..2  in LDS (96 KB)
#define KC_REG 3   // kc 3..5  pinned in VGPRs (48 regs)
#define KC_STR 10  // kc 6..15 streamed from L2, 3-buf rolling prefetch

// Bpack[( (nt*NKC + kc)*64 + lane )*8 + e] = W_hh[n*H + k] as bf16
//   k = kc*32 + (lane>>4)*8 + e,  n = nt*16 + (lane&15)
__global__ void pack_w16(const float* __restrict__ W_hh,
                         unsigned short* __restrict__ Bpack) {
    int idx = blockIdx.x * blockDim.x + threadIdx.x;
    if (idx >= 32 * NKC * 64) return;
    int lane = idx & 63;
    int kc   = (idx >> 6) % NKC;
    int nt   = (idx >> 6) / NKC;
    int n  = nt * 16 + (lane & 15);
    int k0 = kc * 32 + (lane >> 4) * 8;
    unsigned short* dst = Bpack + (size_t)idx * 8;
#pragma unroll
    for (int e = 0; e < 8; ++e)
        dst[e] = f2bf(W_hh[n * H_ + k0 + e]);
}

// xp[((t*16+bg)*512 + n)*16 + bl] = bf16( W_ih[n]·x[16bg+bl][t] + b_ih[n]+b_hh[n] )
// grid (T_/4, 16), block 256 (4 waves). Each block does 4 consecutive t,
// amortizing the W_ih fetch + f2bf 4x. Wave w owns n rows [128w, 128w+128).
__global__ __launch_bounds__(256)
void xproj_k(const float* __restrict__ x,
             const float* __restrict__ W_ih,
             const float* __restrict__ b_ih,
             const float* __restrict__ b_hh,
             unsigned short* __restrict__ xp) {
    const int tid  = threadIdx.x;
    const int lane = tid & 63;
    const int w    = tid >> 6;      // 0..3
    const int mr   = lane & 15;
    const int q    = lane >> 4;
    const int t0   = blockIdx.x * 4;
    const int bg   = blockIdx.y;    // 0..15

    // B fragments from x for 4 t's: col b-local = mr, k = i = kc*32 + q*8 + e
    short8 bf[4][4];
    const float* xb = x + (size_t)(16 * bg + mr) * T_ * I_ + q * 8;
#pragma unroll
    for (int tt = 0; tt < 4; ++tt)
#pragma unroll
        for (int kc = 0; kc < 4; ++kc) {
            const float* p = xb + (size_t)(t0 + tt) * I_ + kc * 32;
            bf[tt][kc] = pack8(*(const float4*)(p), *(const float4*)(p + 4));
        }

#pragma unroll
    for (int mt = 0; mt < 8; ++mt) {
        const int nrow = w * 128 + mt * 16 + mr;     // A row for this lane
        f32x4 a[4];
#pragma unroll
        for (int tt = 0; tt < 4; ++tt) a[tt] = (f32x4)(0.0f);
#pragma unroll
        for (int kc = 0; kc < 4; ++kc) {
            const float* ab = W_ih + (size_t)nrow * I_ + kc * 32 + q * 8;
            short8 af = pack8(*(const float4*)(ab), *(const float4*)(ab + 4));
#pragma unroll
            for (int tt = 0; tt < 4; ++tt)
                a[tt] = __builtin_amdgcn_mfma_f32_16x16x32_bf16(af, bf[tt][kc], a[tt], 0, 0, 0);
        }
        // D: row n-local = q*4+e, col b-local = mr
#pragma unroll
        for (int tt = 0; tt < 4; ++tt) {
            unsigned short* dst = xp + ((size_t)((t0 + tt) * 16 + bg) * 512) * 16;
#pragma unroll
            for (int e = 0; e < 4; ++e) {
                int n = w * 128 + mt * 16 + q * 4 + e;
                float bv = b_ih[n] + b_hh[n];
                dst[(size_t)n * 16 + mr] = f2bf(a[tt][e] + bv);
            }
        }
    }
}

__global__ __launch_bounds__(512)
void rnn_fast(const unsigned short* __restrict__ Bpack,
              const unsigned short* __restrict__ xp,
              const float* __restrict__ fc_w,
              const float* __restrict__ fc_b,
              float* __restrict__ out) {
    __shared__ __align__(16) unsigned short a_lds[2][16 * RS2];            // 33.3 KB
    __shared__ __align__(16) unsigned short w_lds[32 * KC_LDS * 64 * 8];   // 96 KB

    const int tid  = threadIdx.x;
    const int lane = tid & 63;
    const int w    = tid >> 6;      // wave 0..7, owns cols [64w, 64w+64)
    const int q    = lane >> 4;     // 0..3
    const int mr   = lane & 15;
    const int blk  = blockIdx.x;    // batch group
    const int bb   = blk * 16;

    // h0 = 0
    for (int i = tid; i < 16 * RS2; i += 512) a_lds[0][i] = 0;

    // preload LDS-resident W chunks (kc 0..2), fragment layout
    for (int i = tid; i < 32 * KC_LDS * 64; i += 512) {
        int l  = i & 63;
        int kc = (i >> 6) % KC_LDS;
        int nt = (i >> 6) / KC_LDS;
        *(short8*)&w_lds[(size_t)i * 8] =
            *(const short8*)(Bpack + ((size_t)(nt * NKC + kc) * 64 + l) * 8);
    }

    // W_hh kc 3..5, pinned register-resident (48 VGPRs)
    short8 wreg[KC_REG][4];
#pragma unroll
    for (int r = 0; r < KC_REG; ++r)
#pragma unroll
        for (int j = 0; j < 4; ++j)
            wreg[r][j] = *(const short8*)(Bpack +
                ((size_t)((4 * w + j) * NKC + KC_LDS + r) * 64 + lane) * 8);
#pragma unroll
    for (int r = 0; r < KC_REG; ++r)
#pragma unroll
        for (int j = 0; j < 4; ++j)
            asm volatile("" : "+v"(wreg[r][j]));

    __syncthreads();  // a_lds[0] zeros + w_lds visible

    f32x4 acc[4];
    short8 sb[3][4];   // streamed prefetch buffers (3 kc in flight)

    // dense xp: block's tile for step t starts at (t*16+blk)*512*16 elems
    const unsigned short* xpt = xp + ((size_t)blk * 512) * 16;
    const size_t xstride = (size_t)16 * 512 * 16;   // per-t elems

    for (int t = 0; t < T_; ++t) {
        const unsigned short* A = a_lds[t & 1];
        unsigned short* An      = a_lds[(t & 1) ^ 1];

        // streamed W issue: kc 6,7,8 into sb[0..2]
#pragma unroll
        for (int s = 0; s < 3; ++s)
#pragma unroll
            for (int j = 0; j < 4; ++j)
                sb[s][j] = *(const short8*)(Bpack +
                    ((size_t)((4 * w + j) * NKC + KC_LDS + KC_REG + s) * 64 + lane) * 8);

        // xp prefetch (dense: contiguous 512B per wave per j), consumed in epilogue
        ushort4 xpr[4];
#pragma unroll
        for (int j = 0; j < 4; ++j) {
            int col = (4 * w + j) * 16 + mr;
            xpr[j] = *(const ushort4*)(xpt + (size_t)col * 16 + q * 4);
        }

#pragma unroll
        for (int j = 0; j < 4; ++j) acc[j] = (f32x4)(0.0f);

        // --- LDS-resident kcs (0..2) ---
#pragma unroll
        for (int kc = 0; kc < KC_LDS; ++kc) {
            short8 af = *(const short8*)&A[mr * RS2 + kc * 32 + q * 8];
#pragma unroll
            for (int j = 0; j < 4; ++j) {
                short8 bfr = *(const short8*)&w_lds[
                    (size_t)(((4 * w + j) * KC_LDS + kc) * 64 + lane) * 8];
                acc[j] = __builtin_amdgcn_mfma_f32_16x16x32_bf16(af, bfr, acc[j], 0, 0, 0);
            }
        }
        // --- register-resident kcs (3..5) ---
#pragma unroll
        for (int r = 0; r < KC_REG; ++r) {
            short8 af = *(const short8*)&A[mr * RS2 + (KC_LDS + r) * 32 + q * 8];
#pragma unroll
            for (int j = 0; j < 4; ++j)
                acc[j] = __builtin_amdgcn_mfma_f32_16x16x32_bf16(af, wreg[r][j], acc[j], 0, 0, 0);
        }
        // --- streamed kcs (6..15), rolling 3-deep refill ---
#pragma unroll
        for (int s = 0; s < KC_STR; ++s) {
            int kc = KC_LDS + KC_REG + s;
            short8 af = *(const short8*)&A[mr * RS2 + kc * 32 + q * 8];
#pragma unroll
            for (int j = 0; j < 4; ++j)
                acc[j] = __builtin_amdgcn_mfma_f32_16x16x32_bf16(af, sb[s % 3][j], acc[j], 0, 0, 0);
            if (s + 3 < KC_STR) {
#pragma unroll
                for (int j = 0; j < 4; ++j)
                    sb[s % 3][j] = *(const short8*)(Bpack +
                        ((size_t)((4 * w + j) * NKC + kc + 3) * 64 + lane) * 8);
            }
        }

        // epilogue: h_{t+1} = tanh(acc + xp); D row m = q*4+e, col = (4w+j)*16+mr
#pragma unroll
        for (int j = 0; j < 4; ++j) {
            int col = (4 * w + j) * 16 + mr;
            const unsigned short* xj = (const unsigned short*)&xpr[j];
#pragma unroll
            for (int e = 0; e < 4; ++e) {
                float hv = fast_tanh(acc[j][e] + bf2f(xj[e]));
                An[(q * 4 + e) * RS2 + col] = f2bf(hv);
            }
        }
        xpt += xstride;
        __syncthreads();   // h_{t+1} visible; fences A reads vs next overwrite
    }

    // out[b] = h_T[b] . fc_w + fc_b  (32 threads per batch row); h_T in buf 0 (T even)
    {
        const int row = tid >> 5;
        const int l32 = tid & 31;
        float s = 0.0f;
        for (int k = l32; k < H_; k += 32)
            s += bf2f(a_lds[0][row * RS2 + k]) * fc_w[k];
#pragma unroll
        for (int off = 16; off > 0; off >>= 1)
            s += __shfl_down(s, off, 32);
        if (l32 == 0) out[bb + row] = s + fc_b[0];
    }
}

// ---------------------------------------------------------------------------
// FALLBACK PATH — round-0 kernel verbatim (640 KB workspace, measured 1214 µs)
// ---------------------------------------------------------------------------
#define FB_NKC   20
#define FB_NKC_H 16
#define FB_RS   648
#define FB_KC_LDS 4
#define FB_KC_REG 5
#define FB_KC_STR 7

__global__ void pack_w20(const float* __restrict__ W_ih,
                         const float* __restrict__ W_hh,
                         unsigned short* __restrict__ Bpack) {
    int idx = blockIdx.x * blockDim.x + threadIdx.x;
    if (idx >= 32 * FB_NKC * 64) return;
    int lane = idx & 63;
    int kc   = (idx >> 6) % FB_NKC;
    int nt   = (idx >> 6) / FB_NKC;
    int n  = nt * 16 + (lane & 15);
    int k0 = kc * 32 + (lane >> 4) * 8;
    unsigned short* dst = Bpack + (size_t)idx * 8;
#pragma unroll
    for (int e = 0; e < 8; ++e) {
        int k = k0 + e;
        float v = (k < H_) ? W_hh[n * H_ + k] : W_ih[n * I_ + (k - H_)];
        dst[e] = f2bf(v);
    }
}

__global__ __launch_bounds__(512, 2)
void rnn_fb(const float* __restrict__ x,
            const unsigned short* __restrict__ Bpack,
            const float* __restrict__ b_ih,
            const float* __restrict__ b_hh,
            const float* __restrict__ fc_w,
            const float* __restrict__ fc_b,
            float* __restrict__ out) {
    __shared__ __align__(16) unsigned short a_lds[16 * FB_RS];
    __shared__ __align__(16) unsigned short w_lds[32 * FB_KC_LDS * 64 * 8];

    const int tid  = threadIdx.x;
    const int lane = tid & 63;
    const int w    = tid >> 6;
    const int q    = lane >> 4;
    const int mr   = lane & 15;
    const int bb   = blockIdx.x * 16;

    for (int i = tid; i < 16 * FB_RS; i += 512) a_lds[i] = 0;

    for (int i = tid; i < 32 * FB_KC_LDS * 64; i += 512) {
        int l  = i & 63;
        int kc = (i >> 6) & (FB_KC_LDS - 1);
        int nt = i >> 8;
        *(short8*)&w_lds[(size_t)i * 8] =
            *(const short8*)(Bpack + ((size_t)(nt * FB_NKC + kc) * 64 + l) * 8);
    }

    float bias[4];
#pragma unroll
    for (int j = 0; j < 4; ++j) {
        int col = (4 * w + j) * 16 + mr;
        bias[j] = b_ih[col] + b_hh[col];
    }

    short8 wih[4][4];
#pragma unroll
    for (int j = 0; j < 4; ++j)
#pragma unroll
        for (int kx = 0; kx < 4; ++kx)
            wih[j][kx] = *(const short8*)(Bpack +
                ((size_t)((4 * w + j) * FB_NKC + FB_NKC_H + kx) * 64 + lane) * 8);

    short8 wreg[FB_KC_REG][4];
#pragma unroll
    for (int r = 0; r < FB_KC_REG; ++r)
#pragma unroll
        for (int j = 0; j < 4; ++j)
            wreg[r][j] = *(const short8*)(Bpack +
                ((size_t)((4 * w + j) * FB_NKC + FB_KC_LDS + r) * 64 + lane) * 8);

    const int xrow = tid >> 5;
    const int xc   = (tid & 31) * 4;
    const float* xbase = x + (size_t)(bb + xrow) * T_ * I_ + xc;
    float4 xreg = *(const float4*)(xbase);

    __syncthreads();

    f32x4 acc[4];
    short8 sb[3][4];

    for (int t = 0; t < T_; ++t) {
#pragma unroll
        for (int s = 0; s < 3; ++s)
#pragma unroll
            for (int j = 0; j < 4; ++j)
                sb[s][j] = *(const short8*)(Bpack +
                    ((size_t)((4 * w + j) * FB_NKC + FB_KC_LDS + FB_KC_REG + s) * 64 + lane) * 8);

        {
            ushort4 xs;
            xs.x = f2bf(xreg.x); xs.y = f2bf(xreg.y);
            xs.z = f2bf(xreg.z); xs.w = f2bf(xreg.w);
            *(ushort4*)&a_lds[xrow * FB_RS + H_ + xc] = xs;
        }
        __syncthreads();

        if (t + 1 < T_)
            xreg = *(const float4*)(xbase + (size_t)(t + 1) * I_);

#pragma unroll
        for (int j = 0; j < 4; ++j) acc[j] = (f32x4)(0.0f);

#pragma unroll
        for (int kc = 0; kc < FB_KC_LDS; ++kc) {
            short8 af = *(const short8*)&a_lds[mr * FB_RS + kc * 32 + q * 8];
#pragma unroll
            for (int j = 0; j < 4; ++j) {
                short8 bfr = *(const short8*)&w_lds[
                    (size_t)(((4 * w + j) * FB_KC_LDS + kc) * 64 + lane) * 8];
                acc[j] = __builtin_amdgcn_mfma_f32_16x16x32_bf16(af, bfr, acc[j], 0, 0, 0);
            }
        }
#pragma unroll
        for (int r = 0; r < FB_KC_REG; ++r) {
            short8 af = *(const short8*)&a_lds[mr * FB_RS + (FB_KC_LDS + r) * 32 + q * 8];
#pragma unroll
            for (int j = 0; j < 4; ++j)
                acc[j] = __builtin_amdgcn_mfma_f32_16x16x32_bf16(af, wreg[r][j], acc[j], 0, 0, 0);
        }
#pragma unroll
        for (int kx = 0; kx < 4; ++kx) {
            short8 af = *(const short8*)&a_lds[mr * FB_RS + H_ + kx * 32 + q * 8];
#pragma unroll
            for (int j = 0; j < 4; ++j)
                acc[j] = __builtin_amdgcn_mfma_f32_16x16x32_bf16(af, wih[j][kx], acc[j], 0, 0, 0);
        }
#pragma unroll
        for (int s = 0; s < FB_KC_STR; ++s) {
            int kc = FB_KC_LDS + FB_KC_REG + s;
            short8 af = *(const short8*)&a_lds[mr * FB_RS + kc * 32 + q * 8];
#pragma unroll
            for (int j = 0; j < 4; ++j)
                acc[j] = __builtin_amdgcn_mfma_f32_16x16x32_bf16(af, sb[s % 3][j], acc[j], 0, 0, 0);
            if (s + 3 < FB_KC_STR) {
#pragma unroll
                for (int j = 0; j < 4; ++j)
                    sb[s % 3][j] = *(const short8*)(Bpack +
                        ((size_t)((4 * w + j) * FB_NKC + kc + 3) * 64 + lane) * 8);
            }
        }
        __syncthreads();

#pragma unroll
        for (int j = 0; j < 4; ++j) {
            int col = (4 * w + j) * 16 + mr;
#pragma unroll
            for (int e = 0; e < 4; ++e) {
                float hv = fast_tanh(acc[j][e] + bias[j]);
                a_lds[(q * 4 + e) * FB_RS + col] = f2bf(hv);
            }
        }
    }
    __syncthreads();

    {
        const int row = tid >> 5;
        const int l32 = tid & 31;
        float s = 0.0f;
        for (int k = l32; k < H_; k += 32)
            s += bf2f(a_lds[row * FB_RS + k]) * fc_w[k];
#pragma unroll
        for (int off = 16; off > 0; off >>= 1)
            s += __shfl_down(s, off, 32);
        if (l32 == 0) out[bb + row] = s + fc_b[0];
    }
}

// ---------------------------------------------------------------------------

extern "C" void kernel_launch(void* const* d_in, const int* in_sizes, int n_in,
                              void* d_out, int out_size, void* d_ws, size_t ws_size,
                              hipStream_t stream) {
    const float* x    = (const float*)d_in[0];
    const float* W_ih = (const float*)d_in[1];
    const float* W_hh = (const float*)d_in[2];
    const float* b_ih = (const float*)d_in[3];
    const float* b_hh = (const float*)d_in[4];
    const float* fc_w = (const float*)d_in[5];
    const float* fc_b = (const float*)d_in[6];

    const size_t XP_OFF    = (size_t)32 * NKC * 64 * 8 * 2;            // 512 KB
    const size_t NEED_FAST = XP_OFF + (size_t)T_ * H_ * B_ * 2;        // +64 MB (bf16)

    if (ws_size >= NEED_FAST) {
        unsigned short* Bpack = (unsigned short*)d_ws;
        unsigned short* xp = (unsigned short*)((char*)d_ws + XP_OFF);
        pack_w16<<<128, 256, 0, stream>>>(W_hh, Bpack);
        xproj_k<<<dim3(T_ / 4, 16), 256, 0, stream>>>(x, W_ih, b_ih, b_hh, xp);
        rnn_fast<<<16, 512, 0, stream>>>(Bpack, xp, fc_w, fc_b, (float*)d_out);
    } else {
        unsigned short* Bpack = (unsigned short*)d_ws;                 // 640 KB
        pack_w20<<<160, 256, 0, stream>>>(W_ih, W_hh, Bpack);
        rnn_fb<<<16, 512, 0, stream>>>(x, Bpack, b_ih, b_hh, fc_w, fc_b, (float*)d_out);
    }
}